// Round 5
// baseline (287.552 us; speedup 1.0000x reference)
//
#include <hip/hip_runtime.h>
#include <cmath>

#define SEQ 32
#define BB 1024
#define II 2048
#define OO 1024

typedef unsigned short ushortt;

// ---- build idx row (ordered) + idxT ushort4 groups [g][b] + rev scatter (rcnt pre-zeroed) ----
__global__ void build_idx_rev(const float* __restrict__ x, ushortt* __restrict__ idxArr,
                              int* __restrict__ cntArr, int* __restrict__ rcnt,
                              ushortt* __restrict__ rev, ushortt* __restrict__ idxT) {
  int b = blockIdx.x;
  int lane = threadIdx.x;  // 64 threads = 1 wave
  __shared__ ushortt sIdx[256];
  const float* row = x + (long)b * II;
  int base = 0;
  for (int c = 0; c < II / 64; ++c) {
    float val = row[c * 64 + lane];
    unsigned long long m = __ballot(val != 0.0f);
    if (val != 0.0f) {
      int pos = base + __popcll(m & ((1ull << lane) - 1ull));
      if (pos < 256) {
        idxArr[(b << 8) + pos] = (ushortt)(c * 64 + lane);
        sIdx[pos] = (ushortt)(c * 64 + lane);
      }
    }
    base += __popcll(m);
  }
  int cnt = base < 256 ? base : 256;  // uniform across lanes (base from full ballots)
  if (lane == 0) cntArr[b] = cnt;
  __syncthreads();
  // idxT group g = lane covers j = 4g..4g+3, padded with II
  {
    int j0 = lane * 4;
    ushort4 u;
    u.x = (j0 + 0 < cnt) ? sIdx[j0 + 0] : (ushortt)II;
    u.y = (j0 + 1 < cnt) ? sIdx[j0 + 1] : (ushortt)II;
    u.z = (j0 + 2 < cnt) ? sIdx[j0 + 2] : (ushortt)II;
    u.w = (j0 + 3 < cnt) ? sIdx[j0 + 3] : (ushortt)II;
    ((ushort4*)idxT)[(lane << 10) + b] = u;
  }
  for (int j = lane; j < cnt; j += 64) {
    int i = sIdx[j];
    int pos = atomicAdd(&rcnt[i], 1);
    if (pos < 128) rev[((long)i << 7) + pos] = (ushortt)b;
  }
}

// ---------------- dual transpose for z/v ([O][B] -> [B][O]) ----------------
__global__ void transpose2_f32(const float* __restrict__ zC, const float* __restrict__ vC,
                               float* __restrict__ oz, float* __restrict__ ov) {
  __shared__ float t[32][33];
  const float* src = blockIdx.z ? vC : zC;
  float* dst = blockIdx.z ? ov : oz;
  int c0 = blockIdx.x * 32, r0 = blockIdx.y * 32;  // src is OO x BB
  int tx = threadIdx.x, ty = threadIdx.y;
#pragma unroll
  for (int k = 0; k < 4; k++)
    t[ty + k * 8][tx] = src[(long)(r0 + ty + k * 8) * BB + c0 + tx];
  __syncthreads();
#pragma unroll
  for (int k = 0; k < 4; k++)
    dst[(long)(c0 + ty + k * 8) * OO + r0 + tx] = t[tx][ty + k * 8];
}

// ---------------- full 32-step sim, one block per column ----------------
// State in 3 separate fp32 LDS arrays (wL/aG/nG). Index loads are coalesced
// ushort4 groups with ONE-GROUP SOFTWARE PREFETCH: group g+1 is loaded while
// group g's 12 LDS gathers execute, so the vmcnt wait lands a full loop body
// after the load (round-4's dependent load->use chain stalled each group).
// idxT has an 8 KB tail pad so the g==jm4 over-prefetch is in bounds.
// LDS 37.4 KB -> 4 blocks/CU, 32 waves/CU.
__global__ __launch_bounds__(512, 8) void snn_kernel(
    const float* __restrict__ w, const float* __restrict__ bias,
    const ushortt* __restrict__ idxT, const int* __restrict__ cntArr,
    const int* __restrict__ rcnt, const ushortt* __restrict__ rev,
    const ushortt* __restrict__ idxArr,
    float* __restrict__ zC, float* __restrict__ vC, float* __restrict__ outw,
    float dec) {
  int o = blockIdx.x, tid = threadIdx.x, lane = tid & 63, wave = tid >> 6;
  __shared__ float shbuf[9219];
  __shared__ int sCnt, sFlag, cFlag;
  float* wL = shbuf;                    // [0..2048] live w (pad slot 2048 = 0)
  float* aG = shbuf + 2049;             // [0..2048] A, masked 0 when clipped
  float* nG = shbuf + 4098;             // [0..2048] n, masked 0 when clipped
  float* mL = shbuf + 6147;             // 2048 (spike phase)
  int* sList = (int*)(shbuf + 8195);    // 1024 (spike phase)
  float* Sfix = shbuf + 6147;           // 1024 (quiet phase, aliases mL lo)
  float* SnuD = shbuf + 7171;           // 1024 (quiet phase, aliases mL hi)
  float* SAD = shbuf + 8195;            // 1024 (quiet phase, aliases sList)

#pragma unroll
  for (int q = 0; q < 4; ++q) {
    int i = q * 512 + tid;
    wL[i] = w[(long)o * II + i];
    aG[i] = 0.f;
    nG[i] = (float)rcnt[i];
  }
#pragma unroll
  for (int k = 0; k < 2; ++k) {
    int b = k * 512 + tid;
    Sfix[b] = 0.f; SnuD[b] = 0.f; SAD[b] = 0.f;
  }
  if (tid == 0) {
    sFlag = 0; cFlag = 0;
    wL[II] = 0.f; aG[II] = 0.f; nG[II] = 0.f;
  }

  int jmax[2];
#pragma unroll
  for (int k = 0; k < 2; ++k) {
    int c = cntArr[k * 512 + wave * 64 + lane];
#pragma unroll
    for (int off = 32; off > 0; off >>= 1) c = max(c, __shfl_xor(c, off));
    jmax[k] = c;
  }
  float bo = bias[o];
  unsigned clipped = 0;
  bool everSpk = false;
  float p = 1.f, u = 1.f;
  __syncthreads();

  // initial gather: S = sum w, Snu = sum n over act(b) (replaces s0_kernel)
  const ushort4* tpb = (const ushort4*)idxT;
  double S[2];
  float Snu[2], SA[2], v4[2], zk[2];
#pragma unroll
  for (int k = 0; k < 2; ++k) {
    int b = k * 512 + tid;
    double s = 0.0;
    float sn = 0.f;
    int jm4 = (jmax[k] + 3) >> 2;
    const ushort4* tp = tpb + b;
    ushort4 nx = tp[0];
    for (int g = 0; g < jm4; ++g) {
      ushort4 u0 = nx;
      nx = tp[((g + 1) << 10)];  // prefetch next group (pad-safe at g+1==jm4)
      int a_ = u0.x, b_ = u0.y, c_ = u0.z, d_ = u0.w;
      s += (double)wL[a_]; s += (double)wL[b_]; s += (double)wL[c_]; s += (double)wL[d_];
      sn += nG[a_]; sn += nG[b_]; sn += nG[c_]; sn += nG[d_];
    }
    S[k] = s; Snu[k] = sn;
    SA[k] = 0.f; v4[k] = 0.f; zk[k] = 0.f;
  }

  for (int t = 0; t < SEQ; ++t) {
    p *= dec; u *= dec; u += 1.f;
    float spre = u - p;
    // phase A: z/v from S
    int local = 0;
#pragma unroll
    for (int k = 0; k < 2; ++k) {
      float zin = (float)S[k] + bo;
      float nv = v4[k] * dec + zin;
      float z = (nv >= 1.f) ? 1.f : 0.f;
      nv = nv * (1.f - z);
      v4[k] = nv; zk[k] = z;
      if (z != 0.f) local = 1;
    }
    if (local) sFlag = 1;
    __syncthreads();
    int spk = sFlag;

    if (!spk) {
      // quiet step: per-i recurrence + wave-cooperative clip scatter
#pragma unroll
      for (int q = 0; q < 4; ++q) {
        int i = q * 512 + tid;
        bool already = (clipped >> q) & 1u;
        float n = 0.f, atn = 0.f, fix = 0.f;
        bool cl = false;
        if (!already) {
          n = nG[i];
          atn = everSpk ? (dec * aG[i]) : 0.f;
          float dw = -(1e-3f * (p * n + atn));
          float wold = wL[i];
          float pre = wold + dw;
          float wv = fminf(fmaxf(pre, -1.f), 1.f);
          cl = (pre <= -1.f);
          if (cl) {
            clipped |= 1u << q;
            fix = (-1.f - wold) - dw;
            nG[i] = 0.f;
            if (everSpk) aG[i] = 0.f;
          } else if (everSpk) {
            aG[i] = atn;
          }
          wL[i] = wv;
        }
        unsigned long long m = __ballot(cl);
        if (m) {
          if (lane == 0) cFlag = 1;
          while (m) {
            int src = __builtin_ctzll(m);
            m &= m - 1;
            int ii = __shfl(i, src);
            float fx = __shfl(fix, src);
            float mn = -__shfl(n, src);
            float ma = -__shfl(atn, src);
            int rc = rcnt[ii];
            const ushortt* rp = rev + ((long)ii << 7);
            for (int r = lane; r < rc; r += 64) {
              int b2 = rp[r];
              atomicAdd(&Sfix[b2], fx);
              atomicAdd(&SnuD[b2], mn);
              if (everSpk) atomicAdd(&SAD[b2], ma);
            }
          }
        }
      }
      __syncthreads();
      float coefP = 1e-3f * p;
      if (cFlag) {
#pragma unroll
        for (int k = 0; k < 2; ++k) {
          int b = k * 512 + tid;
          S[k] = S[k] - (double)coefP * (double)Snu[k]
                      - (double)1e-3f * (double)(dec * SA[k])
                      + (double)Sfix[b];
          SA[k] = dec * SA[k] + SAD[b];
          Snu[k] = Snu[k] + SnuD[b];
          Sfix[b] = 0.f; SnuD[b] = 0.f; SAD[b] = 0.f;
        }
      } else {
#pragma unroll
        for (int k = 0; k < 2; ++k) {
          S[k] = S[k] - (double)coefP * (double)Snu[k]
                      - (double)1e-3f * (double)(dec * SA[k]);
          SA[k] = dec * SA[k];
        }
      }
      if (tid == 0) { sFlag = 0; cFlag = 0; }
      __syncthreads();
    } else {
      // spike step: exact update via mL, then one re-gather to re-sync aggregates
      everSpk = true;
      if (tid == 0) sCnt = 0;
      __syncthreads();
#pragma unroll
      for (int k = 0; k < 2; ++k)
        if (zk[k] != 0.f) { int pos = atomicAdd(&sCnt, 1); sList[pos] = k * 512 + tid; }
#pragma unroll
      for (int q = 0; q < 4; ++q) mL[q * 512 + tid] = 0.f;
      __syncthreads();
      int ns = sCnt;
      // sparse scatter: mL[i] += 1 over active index list of each spiking batch
      for (int s = wave; s < ns; s += 8) {
        int b = sList[s];
        int cb = cntArr[b];
        const ushortt* ip = idxArr + (b << 8);
        for (int j = lane; j < cb; j += 64)
          atomicAdd(&mL[ip[j]], 1.f);
      }
      __syncthreads();
      float cv = (float)ns;
#pragma unroll
      for (int q = 0; q < 4; ++q) {
        int i = q * 512 + tid;
        float mt = mL[i];
        float atn = dec * aG[i] + mt;
        float n = (float)rcnt[i];  // true n (nG may be masked)
        float dw = 1e-3f * (p * cv + spre * mt) - 1e-3f * (p * n + atn);
        float wold = wL[i];
        float pre = wold + dw;
        float wv = fminf(fmaxf(pre, -1.f), 1.f);
        bool cl = (pre <= -1.f);
        if (cl) clipped |= 1u << q; else clipped &= ~(1u << q);
        wL[i] = wv;
        aG[i] = cl ? 0.f : atn;
        nG[i] = cl ? 0.f : n;
      }
      __syncthreads();  // wL/aG/nG final; mL/sList dead
      // re-gather S (double, ascending-j order), SA, Snu; prefetched ushort4 groups
#pragma unroll
      for (int k = 0; k < 2; ++k) {
        int b = k * 512 + tid;
        double s = 0.0;
        float sa = 0.f, sn = 0.f;
        int jm4 = (jmax[k] + 3) >> 2;
        const ushort4* tp = tpb + b;
        ushort4 nx = tp[0];
        for (int g = 0; g < jm4; ++g) {
          ushort4 u0 = nx;
          nx = tp[((g + 1) << 10)];  // prefetch next group (pad-safe)
          int a_ = u0.x, b_ = u0.y, c_ = u0.z, d_ = u0.w;
          s += (double)wL[a_]; sa += aG[a_]; sn += nG[a_];
          s += (double)wL[b_]; sa += aG[b_]; sn += nG[b_];
          s += (double)wL[c_]; sa += aG[c_]; sn += nG[c_];
          s += (double)wL[d_]; sa += aG[d_]; sn += nG[d_];
        }
        S[k] = s; SA[k] = sa; Snu[k] = sn;
      }
      // restore quiet-phase scatter invariant (region aliased by mL/sList)
#pragma unroll
      for (int k = 0; k < 2; ++k) {
        int b = k * 512 + tid;
        Sfix[b] = 0.f; SnuD[b] = 0.f; SAD[b] = 0.f;
      }
      if (tid == 0) { sFlag = 0; cFlag = 0; }
      __syncthreads();
    }
  }

  __syncthreads();
  // coalesced outputs: w row-major; z/v column-major staging (transposed after)
#pragma unroll
  for (int q = 0; q < 4; ++q) outw[(long)o * II + q * 512 + tid] = wL[q * 512 + tid];
#pragma unroll
  for (int k = 0; k < 2; ++k) {
    int b = k * 512 + tid;
    zC[(long)o * BB + b] = zk[k];
    vC[(long)o * BB + b] = v4[k];
  }
}

extern "C" void kernel_launch(void* const* d_in, const int* in_sizes, int n_in,
                              void* d_out, int out_size, void* d_ws, size_t ws_size,
                              hipStream_t stream) {
  const float* x = (const float*)d_in[0];     // [B, I] {0,1} fp32
  const float* w = (const float*)d_in[1];     // [O, I] fp32
  const float* bias = (const float*)d_in[2];  // [O]
  float* out = (float*)d_out;                 // z[B,O] | v[B,O] | w[O,I]

  char* ws = (char*)d_ws;
  ushortt* idxArr = (ushortt*)(ws + 0);        // 512 KB
  int* cntArr = (int*)(ws + 524288);           // 4 KB
  ushortt* idxT = (ushortt*)(ws + 528384);     // 512 KB + 8 KB prefetch pad
  int* rcnt = (int*)(ws + 1060864);            // 8 KB
  ushortt* rev = (ushortt*)(ws + 1069056);     // 512 KB
  float* zC = (float*)(ws + 1593344);          // 4 MB
  float* vC = (float*)(ws + 5787648);          // 4 MB

  hipMemsetAsync(rcnt, 0, II * sizeof(int), stream);
  build_idx_rev<<<BB, 64, 0, stream>>>(x, idxArr, cntArr, rcnt, rev, idxT);

  const float dec = (float)exp(-0.05);  // shared decay (pre/post/mem)

  snn_kernel<<<OO, 512, 0, stream>>>(w, bias, idxT, cntArr, rcnt, rev, idxArr,
                                     zC, vC, out + 2 * BB * OO, dec);

  // z, v: [O][B] -> [B][O]
  transpose2_f32<<<dim3(BB / 32, OO / 32, 2), dim3(32, 8), 0, stream>>>(zC, vC, out, out + BB * OO);
}

// Round 6
// 276.950 us; speedup vs baseline: 1.0383x; 1.0383x over previous
//
#include <hip/hip_runtime.h>
#include <cmath>

#define SEQ 32
#define BB 1024
#define II 2048
#define OO 1024

typedef unsigned short ushortt;

// ---- build idx row (ordered) + idxT ushort4 groups [g][b] + rev scatter (rcnt pre-zeroed) ----
__global__ void build_idx_rev(const float* __restrict__ x, ushortt* __restrict__ idxArr,
                              int* __restrict__ cntArr, int* __restrict__ rcnt,
                              ushortt* __restrict__ rev, ushortt* __restrict__ idxT) {
  int b = blockIdx.x;
  int lane = threadIdx.x;  // 64 threads = 1 wave
  __shared__ ushortt sIdx[256];
  const float* row = x + (long)b * II;
  int base = 0;
  for (int c = 0; c < II / 64; ++c) {
    float val = row[c * 64 + lane];
    unsigned long long m = __ballot(val != 0.0f);
    if (val != 0.0f) {
      int pos = base + __popcll(m & ((1ull << lane) - 1ull));
      if (pos < 256) {
        idxArr[(b << 8) + pos] = (ushortt)(c * 64 + lane);
        sIdx[pos] = (ushortt)(c * 64 + lane);
      }
    }
    base += __popcll(m);
  }
  int cnt = base < 256 ? base : 256;  // uniform across lanes (base from full ballots)
  if (lane == 0) cntArr[b] = cnt;
  __syncthreads();
  // idxT group g = lane covers j = 4g..4g+3, padded with II
  {
    int j0 = lane * 4;
    ushort4 u;
    u.x = (j0 + 0 < cnt) ? sIdx[j0 + 0] : (ushortt)II;
    u.y = (j0 + 1 < cnt) ? sIdx[j0 + 1] : (ushortt)II;
    u.z = (j0 + 2 < cnt) ? sIdx[j0 + 2] : (ushortt)II;
    u.w = (j0 + 3 < cnt) ? sIdx[j0 + 3] : (ushortt)II;
    ((ushort4*)idxT)[(lane << 10) + b] = u;
  }
  for (int j = lane; j < cnt; j += 64) {
    int i = sIdx[j];
    int pos = atomicAdd(&rcnt[i], 1);
    if (pos < 128) rev[((long)i << 7) + pos] = (ushortt)b;
  }
}

// ---------------- dual transpose for z/v ([O][B] -> [B][O]) ----------------
__global__ void transpose2_f32(const float* __restrict__ zC, const float* __restrict__ vC,
                               float* __restrict__ oz, float* __restrict__ ov) {
  __shared__ float t[32][33];
  const float* src = blockIdx.z ? vC : zC;
  float* dst = blockIdx.z ? ov : oz;
  int c0 = blockIdx.x * 32, r0 = blockIdx.y * 32;  // src is OO x BB
  int tx = threadIdx.x, ty = threadIdx.y;
#pragma unroll
  for (int k = 0; k < 4; k++)
    t[ty + k * 8][tx] = src[(long)(r0 + ty + k * 8) * BB + c0 + tx];
  __syncthreads();
#pragma unroll
  for (int k = 0; k < 4; k++)
    dst[(long)(c0 + ty + k * 8) * OO + r0 + tx] = t[tx][ty + k * 8];
}

// ---------------- full 32-step sim, one block per column ----------------
// The spike re-gather is LDS word-bandwidth bound; this version gathers only
// 2 words/element (wL + aG). Snu (= sum of masked n over act(b)) is integer-
// exact and maintained purely by +/-n rev-list scatters on every clip-status
// FLIP (quiet path: clip only; spike path: both directions) -- the nG array
// is deleted. True n comes from L2-hot rcnt. LDS 32.8 KB -> 4 blocks/CU.
__global__ __launch_bounds__(512, 8) void snn_kernel(
    const float* __restrict__ w, const float* __restrict__ bias,
    const ushortt* __restrict__ idxT, const int* __restrict__ cntArr,
    const int* __restrict__ rcnt, const ushortt* __restrict__ rev,
    const ushortt* __restrict__ idxArr,
    float* __restrict__ zC, float* __restrict__ vC, float* __restrict__ outw,
    float dec) {
  int o = blockIdx.x, tid = threadIdx.x, lane = tid & 63, wave = tid >> 6;
  __shared__ float shbuf[8195];
  __shared__ int sCnt, sFlag, cFlag;
  float* wL = shbuf;                    // [0..2048] live w (pad slot 2048 = 0)
  float* aG = shbuf + 2049;             // [0..2048] A, masked 0 when clipped
  float* mL = shbuf + 4098;             // [0..2048] spike counts (spike phase); slot 2048 = init-nT pad
  int* sList = (int*)(shbuf + 6147);    // 1024 (spike phase)
  float* SnuD = shbuf + 7171;           // 1024 DEDICATED (both phases; flip deltas)
  float* nT = shbuf + 4098;             // init staging of rcnt (aliases mL, init only)
  float* Sfix = shbuf + 4098;           // 1024 (quiet phase, aliases mL lo)
  float* SAD = shbuf + 6147;            // 1024 (quiet phase, aliases sList)

#pragma unroll
  for (int q = 0; q < 4; ++q) {
    int i = q * 512 + tid;
    wL[i] = w[(long)o * II + i];
    aG[i] = 0.f;
    nT[i] = (float)rcnt[i];
  }
#pragma unroll
  for (int k = 0; k < 2; ++k) SnuD[k * 512 + tid] = 0.f;
  if (tid == 0) {
    sFlag = 0; cFlag = 0;
    wL[II] = 0.f; aG[II] = 0.f; nT[II] = 0.f;
  }

  int jmax[2];
#pragma unroll
  for (int k = 0; k < 2; ++k) {
    int c = cntArr[k * 512 + wave * 64 + lane];
#pragma unroll
    for (int off = 32; off > 0; off >>= 1) c = max(c, __shfl_xor(c, off));
    jmax[k] = c;
  }
  float bo = bias[o];
  unsigned clipped = 0;
  bool everSpk = false;
  float p = 1.f, u = 1.f;
  __syncthreads();

  // initial gather: S = sum w, Snu = sum n over act(b) (nothing clipped yet)
  const ushort4* tpb = (const ushort4*)idxT;
  double S[2];
  float Snu[2], SA[2], v4[2], zk[2];
#pragma unroll
  for (int k = 0; k < 2; ++k) {
    int b = k * 512 + tid;
    double s = 0.0;
    float sn = 0.f;
    int jm4 = (jmax[k] + 3) >> 2;
    const ushort4* tp = tpb + b;
    for (int g = 0; g < jm4; ++g) {
      ushort4 u0 = tp[(g << 10)];
      int a_ = u0.x, b_ = u0.y, c_ = u0.z, d_ = u0.w;
      s += (double)wL[a_]; s += (double)wL[b_]; s += (double)wL[c_]; s += (double)wL[d_];
      sn += nT[a_]; sn += nT[b_]; sn += nT[c_]; sn += nT[d_];
    }
    S[k] = s; Snu[k] = sn;
    SA[k] = 0.f; v4[k] = 0.f; zk[k] = 0.f;
  }
  __syncthreads();  // all nT reads done; region becomes Sfix/mL
#pragma unroll
  for (int k = 0; k < 2; ++k) {
    int b = k * 512 + tid;
    Sfix[b] = 0.f; SAD[b] = 0.f;
  }

  for (int t = 0; t < SEQ; ++t) {
    p *= dec; u *= dec; u += 1.f;
    float spre = u - p;
    // phase A: z/v from S
    int local = 0;
#pragma unroll
    for (int k = 0; k < 2; ++k) {
      float zin = (float)S[k] + bo;
      float nv = v4[k] * dec + zin;
      float z = (nv >= 1.f) ? 1.f : 0.f;
      nv = nv * (1.f - z);
      v4[k] = nv; zk[k] = z;
      if (z != 0.f) local = 1;
    }
    if (local) sFlag = 1;
    __syncthreads();
    int spk = sFlag;

    if (!spk) {
      // quiet step: per-i recurrence + wave-cooperative clip scatter
#pragma unroll
      for (int q = 0; q < 4; ++q) {
        int i = q * 512 + tid;
        bool already = (clipped >> q) & 1u;
        float n = 0.f, atn = 0.f, fix = 0.f;
        bool cl = false;
        if (!already) {
          n = (float)rcnt[i];
          atn = everSpk ? (dec * aG[i]) : 0.f;
          float dw = -(1e-3f * (p * n + atn));
          float wold = wL[i];
          float pre = wold + dw;
          float wv = fminf(fmaxf(pre, -1.f), 1.f);
          cl = (pre <= -1.f);
          if (cl) {
            clipped |= 1u << q;
            fix = (-1.f - wold) - dw;
            if (everSpk) aG[i] = 0.f;
          } else if (everSpk) {
            aG[i] = atn;
          }
          wL[i] = wv;
        }
        unsigned long long m = __ballot(cl);
        if (m) {
          if (lane == 0) cFlag = 1;
          while (m) {
            int src = __builtin_ctzll(m);
            m &= m - 1;
            int ii = __shfl(i, src);
            float fx = __shfl(fix, src);
            float mn = -__shfl(n, src);
            float ma = -__shfl(atn, src);
            int rc = rcnt[ii];
            const ushortt* rp = rev + ((long)ii << 7);
            for (int r = lane; r < rc; r += 64) {
              int b2 = rp[r];
              atomicAdd(&Sfix[b2], fx);
              atomicAdd(&SnuD[b2], mn);
              if (everSpk) atomicAdd(&SAD[b2], ma);
            }
          }
        }
      }
      __syncthreads();
      float coefP = 1e-3f * p;
      if (cFlag) {
#pragma unroll
        for (int k = 0; k < 2; ++k) {
          int b = k * 512 + tid;
          S[k] = S[k] - (double)coefP * (double)Snu[k]
                      - (double)1e-3f * (double)(dec * SA[k])
                      + (double)Sfix[b];
          SA[k] = dec * SA[k] + SAD[b];
          Snu[k] = Snu[k] + SnuD[b];
          Sfix[b] = 0.f; SnuD[b] = 0.f; SAD[b] = 0.f;
        }
      } else {
#pragma unroll
        for (int k = 0; k < 2; ++k) {
          S[k] = S[k] - (double)coefP * (double)Snu[k]
                      - (double)1e-3f * (double)(dec * SA[k]);
          SA[k] = dec * SA[k];
        }
      }
      if (tid == 0) { sFlag = 0; cFlag = 0; }
      __syncthreads();
    } else {
      // spike step: exact per-i update via mL; Snu maintained by flip scatters;
      // re-gather only S (wL) and SA (aG) -- 2 LDS words/element.
      everSpk = true;
      if (tid == 0) sCnt = 0;
      __syncthreads();
#pragma unroll
      for (int k = 0; k < 2; ++k)
        if (zk[k] != 0.f) { int pos = atomicAdd(&sCnt, 1); sList[pos] = k * 512 + tid; }
#pragma unroll
      for (int q = 0; q < 4; ++q) mL[q * 512 + tid] = 0.f;
      __syncthreads();
      int ns = sCnt;
      // sparse scatter: mL[i] += 1 over active index list of each spiking batch
      for (int s = wave; s < ns; s += 8) {
        int b = sList[s];
        int cb = cntArr[b];
        const ushortt* ip = idxArr + (b << 8);
        for (int j = lane; j < cb; j += 64)
          atomicAdd(&mL[ip[j]], 1.f);
      }
      __syncthreads();
      float cv = (float)ns;
#pragma unroll
      for (int q = 0; q < 4; ++q) {
        int i = q * 512 + tid;
        float mt = mL[i];
        float atn = dec * aG[i] + mt;
        float n = (float)rcnt[i];  // true n
        float dw = 1e-3f * (p * cv + spre * mt) - 1e-3f * (p * n + atn);
        float wold = wL[i];
        float pre = wold + dw;
        float wv = fminf(fmaxf(pre, -1.f), 1.f);
        bool cl = (pre <= -1.f);
        bool was = (clipped >> q) & 1u;
        if (cl) clipped |= 1u << q; else clipped &= ~(1u << q);
        wL[i] = wv;
        aG[i] = cl ? 0.f : atn;
        // Snu flip scatter: masked-n aggregate changes only on status flips
        bool flip = (cl != was);
        float dn = cl ? -n : n;
        unsigned long long m = __ballot(flip);
        while (m) {
          int src = __builtin_ctzll(m);
          m &= m - 1;
          int ii = __shfl(i, src);
          float d = __shfl(dn, src);
          int rc = rcnt[ii];
          const ushortt* rp = rev + ((long)ii << 7);
          for (int r = lane; r < rc; r += 64)
            atomicAdd(&SnuD[rp[r]], d);
        }
      }
      __syncthreads();  // wL/aG final, SnuD deltas complete; mL/sList dead
      // re-gather S (double, ascending-j order) and SA; Snu from deltas
#pragma unroll
      for (int k = 0; k < 2; ++k) {
        int b = k * 512 + tid;
        double s = 0.0;
        float sa = 0.f;
        int jm4 = (jmax[k] + 3) >> 2;
        const ushort4* tp = tpb + b;
        for (int g = 0; g < jm4; ++g) {
          ushort4 u0 = tp[(g << 10)];
          int a_ = u0.x, b_ = u0.y, c_ = u0.z, d_ = u0.w;
          s += (double)wL[a_]; sa += aG[a_];
          s += (double)wL[b_]; sa += aG[b_];
          s += (double)wL[c_]; sa += aG[c_];
          s += (double)wL[d_]; sa += aG[d_];
        }
        S[k] = s; SA[k] = sa;
        Snu[k] = Snu[k] + SnuD[b];
        SnuD[b] = 0.f;
        Sfix[b] = 0.f; SAD[b] = 0.f;  // restore quiet-phase invariant (aliased regions)
      }
      if (tid == 0) { sFlag = 0; cFlag = 0; }
      __syncthreads();
    }
  }

  __syncthreads();
  // coalesced outputs: w row-major; z/v column-major staging (transposed after)
#pragma unroll
  for (int q = 0; q < 4; ++q) outw[(long)o * II + q * 512 + tid] = wL[q * 512 + tid];
#pragma unroll
  for (int k = 0; k < 2; ++k) {
    int b = k * 512 + tid;
    zC[(long)o * BB + b] = zk[k];
    vC[(long)o * BB + b] = v4[k];
  }
}

extern "C" void kernel_launch(void* const* d_in, const int* in_sizes, int n_in,
                              void* d_out, int out_size, void* d_ws, size_t ws_size,
                              hipStream_t stream) {
  const float* x = (const float*)d_in[0];     // [B, I] {0,1} fp32
  const float* w = (const float*)d_in[1];     // [O, I] fp32
  const float* bias = (const float*)d_in[2];  // [O]
  float* out = (float*)d_out;                 // z[B,O] | v[B,O] | w[O,I]

  char* ws = (char*)d_ws;
  ushortt* idxArr = (ushortt*)(ws + 0);        // 512 KB
  int* cntArr = (int*)(ws + 524288);           // 4 KB
  ushortt* idxT = (ushortt*)(ws + 528384);     // 512 KB + 8 KB pad
  int* rcnt = (int*)(ws + 1060864);            // 8 KB
  ushortt* rev = (ushortt*)(ws + 1069056);     // 512 KB
  float* zC = (float*)(ws + 1593344);          // 4 MB
  float* vC = (float*)(ws + 5787648);          // 4 MB

  hipMemsetAsync(rcnt, 0, II * sizeof(int), stream);
  build_idx_rev<<<BB, 64, 0, stream>>>(x, idxArr, cntArr, rcnt, rev, idxT);

  const float dec = (float)exp(-0.05);  // shared decay (pre/post/mem)

  snn_kernel<<<OO, 512, 0, stream>>>(w, bias, idxT, cntArr, rcnt, rev, idxArr,
                                     zC, vC, out + 2 * BB * OO, dec);

  // z, v: [O][B] -> [B][O]
  transpose2_f32<<<dim3(BB / 32, OO / 32, 2), dim3(32, 8), 0, stream>>>(zC, vC, out, out + BB * OO);
}